// Round 1
// baseline (39.515 us; speedup 1.0000x reference)
//
#include <hip/hip_runtime.h>
#include <hip/hip_bf16.h>

typedef __bf16 bf16x8 __attribute__((ext_vector_type(8)));
typedef float  f32x4  __attribute__((ext_vector_type(4)));

#define NFEAT 128
#define NSAMP 8192
#define GROUPS 32
#define FEAT_PER_GRP 4
#define MT_PER_WAVE 8   // 8 M-tiles of 16 samples = 128 samples per wave

// ---------------------------------------------------------------------------
// Prep: pack W1 (A-operand = W1^T) and W2 (A-operand = W2^T with K-permutation
// pi baked in) into per-lane fragment-linear bf16 buffers.
// Fragment layout assumption (mfma_f32_16x16x32_bf16):
//   A: lane l holds A[row = l&15][k = 8*(l>>4) + j], j = 0..7
//   B: lane l holds B[k = 8*(l>>4) + j][col = l&15]
//   D: lane l reg r holds D[row = 4*(l>>4) + r][col = l&15]
// ---------------------------------------------------------------------------
__global__ __launch_bounds__(256) void nam_prep(const float* __restrict__ W1,
                                                const float* __restrict__ W2,
                                                __bf16* __restrict__ W1p,
                                                __bf16* __restrict__ W2p) {
  int t = blockIdx.x * 256 + threadIdx.x;
  const int n1 = NFEAT * 8 * 64 * 8;          // 524288 elements
  if (t < n1) {
    int j = t & 7, l = (t >> 3) & 63, q = (t >> 9) & 7, f = t >> 12;
    int mt = q >> 1, ks = q & 1;
    int out2 = (l & 15) + 16 * mt;            // A row = output index
    int i1   = 8 * (l >> 4) + j + 32 * ks;    // A k   = input index
    W1p[t] = (__bf16)W1[f * 4096 + i1 * 64 + out2];
  } else {
    int t2 = t - n1;
    const int n2 = NFEAT * 4 * 64 * 8;        // 262144 elements
    if (t2 < n2) {
      int j = t2 & 7, l = (t2 >> 3) & 63, q = (t2 >> 9) & 3, f = t2 >> 11;
      int mt3 = q >> 1, ks = q & 1;
      int out3 = (l & 15) + 16 * mt3;
      int g = l >> 4;
      // K-permutation pi: slot (ks,g,j) -> i2 so that the lane-held h2
      // registers (out2 = 16*mt + 4*g + r) line up with B-fragment slots.
      int i2 = 32 * ks + 16 * (j >> 2) + 4 * g + (j & 3);
      W2p[t2] = (__bf16)W2[f * 2048 + i2 * 32 + out3];
    }
  }
}

// ---------------------------------------------------------------------------
// Main: one wave per block. Wave owns 128 samples (8 M-tiles) x 4 features.
// Swapped MFMA: D[out][sample]; b1/b2 folded into MFMA C-init. No LDS.
// ---------------------------------------------------------------------------
__global__ __launch_bounds__(64) void nam_main(
    const float* __restrict__ X, const float* __restrict__ W0,
    const float* __restrict__ b0, const float* __restrict__ b1,
    const float* __restrict__ b2, const float* __restrict__ W3,
    const float* __restrict__ b3, const bf16x8* __restrict__ W1p,
    const bf16x8* __restrict__ W2p, float* __restrict__ part) {
  const int l  = threadIdx.x;            // 0..63
  const int lg = l >> 4, ls = l & 15;
  const int blk   = blockIdx.x;
  const int chunk = blk & 63;            // 64 chunks of 128 samples
  const int grp   = blk >> 6;            // 32 feature groups
  const int n0 = chunk * 128;
  const int f0 = grp * FEAT_PER_GRP;

  float acc[MT_PER_WAVE];
#pragma unroll
  for (int m = 0; m < MT_PER_WAVE; ++m) acc[m] = 0.f;

  for (int ff = 0; ff < FEAT_PER_GRP; ++ff) {
    const int f = f0 + ff;
    // ---- per-feature weight fragments (coalesced 16B/lane) ----
    bf16x8 w1f[8];                       // [mt*2 + ks]
#pragma unroll
    for (int q = 0; q < 8; ++q) w1f[q] = W1p[(f * 8 + q) * 64 + l];
    bf16x8 w2f[4];                       // [mt3*2 + ks]
#pragma unroll
    for (int q = 0; q < 4; ++q) w2f[q] = W2p[(f * 4 + q) * 64 + l];
    f32x4 b1f[4], b2f[2], w3f[2];
#pragma unroll
    for (int mt = 0; mt < 4; ++mt)
      b1f[mt] = *(const f32x4*)(b1 + f * 64 + 16 * mt + 4 * lg);
#pragma unroll
    for (int mt = 0; mt < 2; ++mt)
      b2f[mt] = *(const f32x4*)(b2 + f * 32 + 16 * mt + 4 * lg);
#pragma unroll
    for (int mt = 0; mt < 2; ++mt)
      w3f[mt] = *(const f32x4*)(W3 + f * 32 + 16 * mt + 4 * lg);
    f32x4 w0q[4], b0q[4];                // [ks*2 + half], fp32 layer-1 weights
#pragma unroll
    for (int ks = 0; ks < 2; ++ks)
#pragma unroll
      for (int hh = 0; hh < 2; ++hh) {
        w0q[ks * 2 + hh] = *(const f32x4*)(W0 + f * 64 + 32 * ks + 8 * lg + 4 * hh);
        b0q[ks * 2 + hh] = *(const f32x4*)(b0 + f * 64 + 32 * ks + 8 * lg + 4 * hh);
      }
    const float b3v = b3[f];

#pragma unroll
    for (int m = 0; m < MT_PER_WAVE; ++m) {
      const float xv = X[(n0 + 16 * m + ls) * NFEAT + f];
      // ---- layer 1 (fp32) -> B-fragment of L2 (h1^T), in-lane ----
      bf16x8 a1[2];
#pragma unroll
      for (int ks = 0; ks < 2; ++ks)
#pragma unroll
        for (int j = 0; j < 8; ++j) {
          float h = fmaf(xv, w0q[ks * 2 + (j >> 2)][j & 3],
                         b0q[ks * 2 + (j >> 2)][j & 3]);
          a1[ks][j] = (__bf16)fmaxf(h, 0.f);
        }
      // ---- layer 2: D[out2][sample], C-init = b1 ----
      f32x4 h2[4];
#pragma unroll
      for (int mt = 0; mt < 4; ++mt) {
        f32x4 c = b1f[mt];
        c = __builtin_amdgcn_mfma_f32_16x16x32_bf16(w1f[mt * 2 + 0], a1[0], c, 0, 0, 0);
        c = __builtin_amdgcn_mfma_f32_16x16x32_bf16(w1f[mt * 2 + 1], a1[1], c, 0, 0, 0);
        h2[mt] = c;
      }
      // ---- relu + pack: lane-held h2 -> L3 B-fragments (pi-permuted K) ----
      bf16x8 bfr[2];
#pragma unroll
      for (int ks = 0; ks < 2; ++ks)
#pragma unroll
        for (int j = 0; j < 8; ++j) {
          float v = h2[2 * ks + (j >> 2)][j & 3];
          bfr[ks][j] = (__bf16)fmaxf(v, 0.f);
        }
      // ---- layer 3: D[out3][sample], C-init = b2 ----
      f32x4 h3[2];
#pragma unroll
      for (int mt = 0; mt < 2; ++mt) {
        f32x4 c = b2f[mt];
        c = __builtin_amdgcn_mfma_f32_16x16x32_bf16(w2f[mt * 2 + 0], bfr[0], c, 0, 0, 0);
        c = __builtin_amdgcn_mfma_f32_16x16x32_bf16(w2f[mt * 2 + 1], bfr[1], c, 0, 0, 0);
        h3[mt] = c;
      }
      // ---- epilogue: relu, dot with w3 (per-lane partial over 8 outs) ----
      float p = (lg == 0) ? b3v : 0.f;
#pragma unroll
      for (int mt = 0; mt < 2; ++mt)
#pragma unroll
        for (int r = 0; r < 4; ++r)
          p = fmaf(fmaxf(h3[mt][r], 0.f), w3f[mt][r], p);
      acc[m] += p;
    }
  }
  // ---- reduce partial contribs across the 4 lane-groups, store ----
#pragma unroll
  for (int m = 0; m < MT_PER_WAVE; ++m) {
    float v = acc[m];
    v += __shfl_xor(v, 16, 64);
    v += __shfl_xor(v, 32, 64);
    if (l < 16) part[grp * NSAMP + n0 + 16 * m + l] = v;
  }
}

// ---------------------------------------------------------------------------
// Reduce: out[n] = bias + sum_g part[g][n]  (fixed order -> deterministic)
// ---------------------------------------------------------------------------
__global__ __launch_bounds__(256) void nam_reduce(const float* __restrict__ part,
                                                  const float* __restrict__ bias,
                                                  float* __restrict__ out) {
  int n = blockIdx.x * 256 + threadIdx.x;
  float s = bias[0];
#pragma unroll
  for (int g = 0; g < GROUPS; ++g) s += part[g * NSAMP + n];
  out[n] = s;
}

// ---------------------------------------------------------------------------
// Fallback (only if ws too small): naive fp32, correct but slow.
// ---------------------------------------------------------------------------
__global__ void nam_naive(const float* __restrict__ X, const float* __restrict__ W0,
                          const float* __restrict__ b0, const float* __restrict__ W1,
                          const float* __restrict__ b1, const float* __restrict__ W2,
                          const float* __restrict__ b2, const float* __restrict__ W3,
                          const float* __restrict__ b3, const float* __restrict__ bias,
                          float* __restrict__ out) {
  int n = blockIdx.x * 64 + threadIdx.x;
  if (n >= NSAMP) return;
  float s = bias[0];
  for (int f = 0; f < NFEAT; ++f) {
    float xv = X[n * NFEAT + f];
    float h1[64], h2[64];
    for (int i = 0; i < 64; ++i)
      h1[i] = fmaxf(fmaf(xv, W0[f * 64 + i], b0[f * 64 + i]), 0.f);
    for (int k = 0; k < 64; ++k) {
      float t = b1[f * 64 + k];
      for (int i = 0; i < 64; ++i) t = fmaf(h1[i], W1[f * 4096 + i * 64 + k], t);
      h2[k] = fmaxf(t, 0.f);
    }
    float c = b3[f];
    for (int k = 0; k < 32; ++k) {
      float t = b2[f * 32 + k];
      for (int i = 0; i < 64; ++i) t = fmaf(h2[i], W2[f * 2048 + i * 32 + k], t);
      c = fmaf(fmaxf(t, 0.f), W3[f * 32 + k], c);
    }
    s += c;
  }
  out[n] = s;
}

extern "C" void kernel_launch(void* const* d_in, const int* in_sizes, int n_in,
                              void* d_out, int out_size, void* d_ws, size_t ws_size,
                              hipStream_t stream) {
  const float* X    = (const float*)d_in[0];
  const float* W0   = (const float*)d_in[1];
  const float* b0   = (const float*)d_in[2];
  const float* W1   = (const float*)d_in[3];
  const float* b1   = (const float*)d_in[4];
  const float* W2   = (const float*)d_in[5];
  const float* b2   = (const float*)d_in[6];
  const float* W3   = (const float*)d_in[7];
  const float* b3   = (const float*)d_in[8];
  const float* bias = (const float*)d_in[9];
  float* out = (float*)d_out;

  const size_t W1P_BYTES  = (size_t)NFEAT * 8 * 64 * 16;  // 1 MiB
  const size_t W2P_BYTES  = (size_t)NFEAT * 4 * 64 * 16;  // 512 KiB
  const size_t PART_BYTES = (size_t)GROUPS * NSAMP * 4;   // 1 MiB
  if (ws_size < W1P_BYTES + W2P_BYTES + PART_BYTES) {
    nam_naive<<<NSAMP / 64, 64, 0, stream>>>(X, W0, b0, W1, b1, W2, b2, W3, b3, bias, out);
    return;
  }
  __bf16* W1p  = (__bf16*)d_ws;
  __bf16* W2p  = (__bf16*)((char*)d_ws + W1P_BYTES);
  float*  partb = (float*)((char*)d_ws + W1P_BYTES + W2P_BYTES);

  nam_prep<<<3072, 256, 0, stream>>>(W1, W2, W1p, W2p);
  nam_main<<<2048, 64, 0, stream>>>(X, W0, b0, b1, b2, W3, b3,
                                    (const bf16x8*)W1p, (const bf16x8*)W2p, partb);
  nam_reduce<<<NSAMP / 256, 256, 0, stream>>>(partb, bias, out);
}